// Round 8
// baseline (3868.865 us; speedup 1.0000x reference)
//
#include <hip/hip_runtime.h>

// ---------------- problem constants ----------------
#define B_ 32
#define S_ 64
#define C_ 512
#define E_ 256
#define H_ 512
#define V_ 32000
#define T_ 32
#define NBLK 256       // grid blocks (persistent kernel)
#define NTHR 512       // threads per block (8 waves)
#define ND 250         // scan blocks (250*128 = 32000)
#define START_TOK 1
#define DELTA 0.05f    // refine margin (bf16 logit err sigma ~6e-4)
#define BH (B_ * H_)

// ---------------- workspace layout (float offsets) ----------------
#define OFF_BAR  0          // monotonic barrier: 16 cnt @g*32, top @512, 16 gen @544+g*32
#define OFF_CS   1280       // cscore[32][64]
#define OFF_LSEA 3328       // lse[32 t][32 b]
#define OFF_TOK  4352       // token flag[32] (int: (t<<15)|tok)
#define OFF_A2V  4416       // top2 cand value [32 b][512] (500 used)
#define OFF_A2I  20800      // top2 cand index [32 b][512] (int)
#define OFF_LSM  37184      // lse partial max [32][256] (250 used)
#define OFF_LSS  45376      // lse partial sum [32][256]
#define OFF_INP  53568      // attend [32 b][512]
#define OFF_H0   69952      // h0[2][32 b][512] ping-pong
#define OFF_H1   102720     // h1[2][32 b][512] ping-pong
#define OFF_H1BF 135488     // ushort[1024][512] bf16 h1 history = 262144 floats
#define OFF_WOBF 397632     // ushort[32000][512] bf16 Wo  (= OFF_H1BF + 262144; r7 bug: was 266560 -> h1bf t>=16 clobbered Wo rows 0..4095)
#define WS_FLOATS 8589632   // ~34.4 MB

typedef unsigned long long ull;
typedef __attribute__((ext_vector_type(8))) short bf16x8;
typedef __attribute__((ext_vector_type(4))) float f32x4;

struct Params {
  const float* ctx; const float* embed; const float* Wa;
  const float* Wih0; const float* Whh0; const float* bih0; const float* bhh0;
  const float* Wih1; const float* Whh1; const float* bih1; const float* bhh1;
  const float* Wo; const float* bo;
  float* ws; float* out;
};

__device__ __forceinline__ float sigf(float x) { return 1.0f / (1.0f + expf(-x)); }

__device__ __forceinline__ unsigned short f2bf(float f) {  // RNE f32->bf16
  unsigned u = __builtin_bit_cast(unsigned, f);
  unsigned r = (u + 0x7FFFu + ((u >> 16) & 1u)) >> 16;
  return (unsigned short)r;
}

__device__ __forceinline__ void lse_merge(float& m, float& s, float m2, float s2) {
  float M = fmaxf(m, m2);
  s = s * expf(m - M) + s2 * expf(m2 - M);
  m = M;
}

// ---- coherent (L2-bypass) access for mutable cross-block data ----
__device__ __forceinline__ float ld_cf(const float* p) {
  return __hip_atomic_load(p, __ATOMIC_RELAXED, __HIP_MEMORY_SCOPE_AGENT);
}
__device__ __forceinline__ void st_cf(float* p, float v) {
  __hip_atomic_store(p, v, __ATOMIC_RELAXED, __HIP_MEMORY_SCOPE_AGENT);
}
__device__ __forceinline__ int ld_ci(const int* p) {
  return __hip_atomic_load(p, __ATOMIC_RELAXED, __HIP_MEMORY_SCOPE_AGENT);
}
__device__ __forceinline__ void st_ci(int* p, int v) {
  __hip_atomic_store(p, v, __ATOMIC_RELAXED, __HIP_MEMORY_SCOPE_AGENT);
}

// -------- monotonic 2-level grid barrier (no resets, minimal dep chain) --------
// cnt[g] (16 groups x 16 blocks) never reset; leader when pre-add == 16*inst-1.
// top never reset; last leader broadcasts inst to 16 gen lines. Per-wave vmcnt
// drain at entry (all waves, not just wave 0).
__device__ __forceinline__ void gbar(unsigned* ws, unsigned inst) {
  asm volatile("s_waitcnt vmcnt(0) lgkmcnt(0)" ::: "memory");
  __syncthreads();
  if (threadIdx.x == 0) {
    unsigned* cnt = ws + ((blockIdx.x & 15) << 5);
    unsigned* top = ws + 512;
    unsigned* gen = ws + 544 + ((blockIdx.x & 15) << 5);
    unsigned a = __hip_atomic_fetch_add(cnt, 1u, __ATOMIC_RELAXED, __HIP_MEMORY_SCOPE_AGENT);
    if (a == inst * 16u - 1u) {
      unsigned a2 = __hip_atomic_fetch_add(top, 1u, __ATOMIC_RELAXED, __HIP_MEMORY_SCOPE_AGENT);
      if (a2 == inst * 16u - 1u) {
#pragma unroll
        for (int g = 0; g < 16; ++g)
          __hip_atomic_store(ws + 544 + (g << 5), inst,
                             __ATOMIC_RELAXED, __HIP_MEMORY_SCOPE_AGENT);
      }
    }
    while (__hip_atomic_load(gen, __ATOMIC_RELAXED, __HIP_MEMORY_SCOPE_AGENT) < inst)
      __builtin_amdgcn_s_sleep(1);
    asm volatile("" ::: "memory");
  }
  __syncthreads();
}

// ---------------- prologue kernels ----------------
__global__ void __launch_bounds__(256) zero_k(float* wsf) {
  const unsigned i = blockIdx.x * 256u + threadIdx.x;
  if (i < 1280u) ((unsigned*)wsf)[i] = 0u;
  if (i < 65536u) wsf[OFF_H0 + i] = 0.0f;   // h0[2] + h1[2] contiguous
}

__global__ void __launch_bounds__(256) cscore_k(const float* __restrict__ ctx,
                                                const float* __restrict__ Wa,
                                                const float* __restrict__ ba,
                                                float* __restrict__ wsf) {
  const int b = blockIdx.x;
  const int s = threadIdx.x >> 2, q = threadIdx.x & 3;
  const float* cp = ctx + ((size_t)b * S_ + s) * C_ + q * 128;
  const float* wp = Wa + H_ + q * 128;     // context half of Wa
  float acc = 0.f;
#pragma unroll 8
  for (int k = 0; k < 128; ++k) acc = fmaf(cp[k], wp[k], acc);
  acc += __shfl_xor(acc, 1);
  acc += __shfl_xor(acc, 2);
  if (q == 0) wsf[OFF_CS + b * S_ + s] = acc + ba[0];
}

__global__ void __launch_bounds__(256) cvt_wobf(const float* __restrict__ wo,
                                                unsigned short* __restrict__ dst) {
  const size_t i = ((size_t)blockIdx.x * 256u + threadIdx.x) * 4;
  float4 v = *(const float4*)(wo + i);
  ushort4 o;
  o.x = f2bf(v.x); o.y = f2bf(v.y); o.z = f2bf(v.z); o.w = f2bf(v.w);
  *(ushort4*)(dst + i) = o;
}

// ---------------- main persistent kernel ----------------
__global__ void __launch_bounds__(NTHR) mtad_main(Params p) {
  float* wsf = p.ws;
  int* wsi = (int*)p.ws;
  unsigned* barp = (unsigned*)p.ws;
  unsigned short* h1bf = (unsigned short*)(wsf + OFF_H1BF);
  const unsigned short* wobf = (const unsigned short*)(wsf + OFF_WOBF);
  const int bk = blockIdx.x, tx = threadIdx.x;
  const int ug = bk & 31, bg = bk >> 5, b4 = bg * 4;

  __shared__ __align__(16) unsigned char woL[131072];  // 128 KB bf16 Wo rows (swizzled)
  __shared__ __align__(16) char SMEM[26624];           // phase-dependent blob
  __shared__ float wlds[64];
  __shared__ float hout[64];
  __shared__ int   stok4[4];
  __shared__ float shsS, sMax;
  __shared__ int   slist[64];
  __shared__ int   scnt;

  unsigned bi = 0;   // barrier instance counter (uniform across blocks)

  // ---------- prologue: fill woL (swizzled); attention for t=0 on blocks 0..31 ----------
  if (bk < ND) {
    const unsigned short* src = wobf + (size_t)bk * 128 * H_;
    for (int c = tx; c < 8192; c += NTHR) {
      const int row = c >> 6, cc = c & 63;
      uint4 v = *(const uint4*)(src + (size_t)row * H_ + cc * 8);
      *(uint4*)&woL[row * 1024 + ((cc * 16) ^ ((row & 7) << 4))] = v;
    }
  }
  if (bk < B_) {   // attention t=0 (h1 = 0 -> hscore = 0)
    const int b = bk;
    if (tx < S_) {
      float sc = tanhf(wsf[OFF_CS + b * S_ + tx]);
      float e = expf(sc); float sum = e;
#pragma unroll
      for (int d = 1; d < 64; d <<= 1) sum += __shfl_xor(sum, d);
      float w = e / sum; wlds[tx] = w;
      p.out[(size_t)B_ * T_ * V_ + ((size_t)b * T_ + 0) * S_ + tx] = w;
    }
    __syncthreads();
    float a0 = 0.f;
    const float* cb = p.ctx + (size_t)b * S_ * C_ + tx;
#pragma unroll 8
    for (int s2 = 0; s2 < S_; ++s2) a0 = fmaf(wlds[s2], cb[(size_t)s2 * C_], a0);
    st_cf(wsf + OFF_INP + (size_t)b * H_ + tx, a0);
  }
  gbar(barp, ++bi);

  for (int t = 0; t < T_; ++t) {
    const int par = t & 1;
    // ===== P1: resolve(t) on blocks 32..63 (t>0), then GRU0 on all blocks =====
    {
      float* sacts = (float*)SMEM;            // [4][768]
      float* sh0l  = (float*)(SMEM + 12288);  // [4][512]
      if (bk >= B_ && bk < 2 * B_ && t > 0) {
        const int b = bk - B_;
        float* rtmp = (float*)SMEM;                 // [512] (pre-staging, safe)
        float* rm   = (float*)(SMEM + 20480);       // [256]
        float* rs   = (float*)(SMEM + 21504);       // [256]
        float* sh1r = (float*)(SMEM + 22528);       // [512]
        sh1r[tx] = ld_cf(wsf + OFF_H1 + par * BH + (size_t)b * H_ + tx);
        float cv = -3.0e38f; int ci = 0x7fffffff;
        if (tx < 2 * ND) {
          cv = ld_cf(wsf + OFF_A2V + (size_t)b * 512 + tx);
          ci = ld_ci(wsi + OFF_A2I + (size_t)b * 512 + tx);
        }
        if (tx < 256) {
          rm[tx] = (tx < ND) ? ld_cf(wsf + OFF_LSM + (size_t)b * 256 + tx) : -3.0e38f;
          rs[tx] = (tx < ND) ? ld_cf(wsf + OFF_LSS + (size_t)b * 256 + tx) : 0.f;
        }
        rtmp[tx] = cv;
        __syncthreads();
        if (tx < 256) rtmp[tx] = fmaxf(rtmp[tx], rtmp[tx + 256]);
        if (tx < 128) lse_merge(rm[tx], rs[tx], rm[tx + 128], rs[tx + 128]);
        __syncthreads();
        if (tx < 64) {
          float M = fmaxf(fmaxf(rtmp[tx], rtmp[tx + 64]),
                          fmaxf(rtmp[tx + 128], rtmp[tx + 192]));
          float m = rm[tx], s = rs[tx];
          lse_merge(m, s, rm[tx + 64], rs[tx + 64]);
#pragma unroll
          for (int d = 1; d < 64; d <<= 1) {
            M = fmaxf(M, __shfl_xor(M, d));
            float m2 = __shfl_xor(m, d), s2 = __shfl_xor(s, d);
            lse_merge(m, s, m2, s2);
          }
          if (tx == 0) {
            sMax = M; scnt = 0;
            st_cf(wsf + OFF_LSEA + (t - 1) * B_ + b, m + logf(s));
          }
        }
        __syncthreads();
        if (cv >= sMax - DELTA && ci < V_) {
          int k = atomicAdd(&scnt, 1);
          if (k < 64) slist[k] = ci;
        }
        __syncthreads();
        const int nc = min(scnt, 64);
        float bV = -3.0e38f; int bI = 0x7fffffff;    // thread 0 carries
        for (int c2 = 0; c2 < nc; ++c2) {
          const int idx = slist[c2];
          rtmp[tx] = sh1r[tx] * p.Wo[(size_t)idx * H_ + tx];
          __syncthreads();
          if (tx < 256) rtmp[tx] += rtmp[tx + 256];
          __syncthreads();
          if (tx < 64) {
            float v = rtmp[tx] + rtmp[tx + 64] + rtmp[tx + 128] + rtmp[tx + 192];
#pragma unroll
            for (int d = 1; d < 64; d <<= 1) v += __shfl_xor(v, d);
            if (tx == 0) {
              float ex = v + p.bo[idx];
              if (ex > bV || (ex == bV && idx < bI)) { bV = ex; bI = idx; }
            }
          }
          __syncthreads();
        }
        if (tx == 0) st_ci(wsi + OFF_TOK + b, (t << 15) | bI);
      }
      // --- stage attend + h0prev (all blocks) ---
      {
        ull va[2], vh[2];
#pragma unroll
        for (int k = 0; k < 2; ++k) {
          const int iu = k * NTHR + tx;        // 0..1023
          const int bb = iu >> 8, cc = iu & 255;
          const ull* a1 = (const ull*)(wsf + OFF_INP) + (size_t)(b4 + bb) * 256 + cc;
          const ull* a2 = (const ull*)(wsf + OFF_H0 + par * BH) + (size_t)(b4 + bb) * 256 + cc;
          asm volatile("global_load_dwordx2 %0, %1, off sc0 sc1" : "=v"(va[k]) : "v"(a1));
          asm volatile("global_load_dwordx2 %0, %1, off sc0 sc1" : "=v"(vh[k]) : "v"(a2));
        }
        asm volatile("s_waitcnt vmcnt(0)" ::: "memory");
#pragma unroll
        for (int k = 0; k < 2; ++k) {
          const int iu = k * NTHR + tx;
          const int bb = iu >> 8, cc = iu & 255;
          *(ull*)&sacts[bb * 768 + 256 + cc * 2] = va[k];
          *(ull*)&sh0l[bb * 512 + cc * 2] = vh[k];
        }
      }
      __syncthreads();
      const int u = tx >> 5, l = tx & 31;
      const int j = ug * 16 + u;
      float red[16];
#pragma unroll
      for (int q = 0; q < 16; ++q) red[q] = 0.f;
      // partial gates: attend x-part (c=2..5) + hidden part (c=0..3), float4 LDS
#pragma unroll
      for (int g = 0; g < 3; ++g) {
        const float4* wx = (const float4*)(p.Wih0 + (size_t)(g * H_ + j) * 768);
        float* dx = (g < 2) ? &red[g * 4] : &red[8];
#pragma unroll
        for (int c = 2; c < 6; ++c) {
          float4 w = wx[l + 32 * c];
#pragma unroll
          for (int b2 = 0; b2 < 4; ++b2) {
            const float* a = &sacts[b2 * 768 + 4 * l + 128 * c];
            dx[b2] = fmaf(w.x, a[0], dx[b2]); dx[b2] = fmaf(w.y, a[1], dx[b2]);
            dx[b2] = fmaf(w.z, a[2], dx[b2]); dx[b2] = fmaf(w.w, a[3], dx[b2]);
          }
        }
        const float4* wh = (const float4*)(p.Whh0 + (size_t)(g * H_ + j) * H_);
        float* dh = (g < 2) ? &red[g * 4] : &red[12];
#pragma unroll
        for (int c = 0; c < 4; ++c) {
          float4 w = wh[l + 32 * c];
#pragma unroll
          for (int b2 = 0; b2 < 4; ++b2) {
            const float* a = &sh0l[b2 * 512 + 4 * l + 128 * c];
            dh[b2] = fmaf(w.x, a[0], dh[b2]); dh[b2] = fmaf(w.y, a[1], dh[b2]);
            dh[b2] = fmaf(w.z, a[2], dh[b2]); dh[b2] = fmaf(w.w, a[3], dh[b2]);
          }
        }
      }
      // token pickup (epoch-tagged spin, no barrier)
      if (tx < 4) {
        int tok = START_TOK;
        if (t > 0) {
          int v;
          do {
            v = ld_ci(wsi + OFF_TOK + b4 + tx);
            if (((unsigned)v >> 15) != (unsigned)t) __builtin_amdgcn_s_sleep(1);
          } while (((unsigned)v >> 15) != (unsigned)t);
          tok = v & 0x7fff;
        }
        stok4[tx] = tok;
      }
      __syncthreads();
      // stage embed -> sacts cols [0,256)
#pragma unroll
      for (int k = 0; k < 2; ++k) {
        const int idx = k * NTHR + tx;
        const int bb = idx >> 8, e = idx & 255;
        sacts[bb * 768 + e] = p.embed[(size_t)stok4[bb] * E_ + e];
      }
      __syncthreads();
      // embed x-part (c=0,1)
#pragma unroll
      for (int g = 0; g < 3; ++g) {
        const float4* wx = (const float4*)(p.Wih0 + (size_t)(g * H_ + j) * 768);
        float* dx = (g < 2) ? &red[g * 4] : &red[8];
#pragma unroll
        for (int c = 0; c < 2; ++c) {
          float4 w = wx[l + 32 * c];
#pragma unroll
          for (int b2 = 0; b2 < 4; ++b2) {
            const float* a = &sacts[b2 * 768 + 4 * l + 128 * c];
            dx[b2] = fmaf(w.x, a[0], dx[b2]); dx[b2] = fmaf(w.y, a[1], dx[b2]);
            dx[b2] = fmaf(w.z, a[2], dx[b2]); dx[b2] = fmaf(w.w, a[3], dx[b2]);
          }
        }
      }
#pragma unroll
      for (int d = 1; d < 32; d <<= 1)
#pragma unroll
        for (int q = 0; q < 16; ++q) red[q] += __shfl_xor(red[q], d);
      if (l < 4) {
        const float rr = sigf(red[l] + p.bih0[j] + p.bhh0[j]);
        const float zz = sigf(red[4 + l] + p.bih0[H_ + j] + p.bhh0[H_ + j]);
        const float nn = tanhf(red[8 + l] + p.bih0[2 * H_ + j] +
                               rr * (red[12 + l] + p.bhh0[2 * H_ + j]));
        const float hp = sh0l[l * 512 + j];
        st_cf(wsf + OFF_H0 + (1 - par) * BH + (size_t)(b4 + l) * H_ + j,
              (1.f - zz) * nn + zz * hp);
      }
    }
    gbar(barp, ++bi);
    // ================= P2: GRU layer 1 + packs =================
    {
      float* sx = (float*)SMEM;                 // [4][512] h0_new
      float* sh = (float*)(SMEM + 8192);        // [4][512] h1_prev
      {
        ull vx[2], vh2[2];
#pragma unroll
        for (int k = 0; k < 2; ++k) {
          const int iu = k * NTHR + tx;
          const int bb = iu >> 8, cc = iu & 255;
          const ull* a1 = (const ull*)(wsf + OFF_H0 + (1 - par) * BH) + (size_t)(b4 + bb) * 256 + cc;
          const ull* a2 = (const ull*)(wsf + OFF_H1 + par * BH) + (size_t)(b4 + bb) * 256 + cc;
          asm volatile("global_load_dwordx2 %0, %1, off sc0 sc1" : "=v"(vx[k]) : "v"(a1));
          asm volatile("global_load_dwordx2 %0, %1, off sc0 sc1" : "=v"(vh2[k]) : "v"(a2));
        }
        asm volatile("s_waitcnt vmcnt(0)" ::: "memory");
#pragma unroll
        for (int k = 0; k < 2; ++k) {
          const int iu = k * NTHR + tx;
          const int bb = iu >> 8, cc = iu & 255;
          *(ull*)&sx[bb * 512 + cc * 2] = vx[k];
          *(ull*)&sh[bb * 512 + cc * 2] = vh2[k];
        }
      }
      __syncthreads();
      const int u = tx >> 5, l = tx & 31;
      const int j = ug * 16 + u;
      float red[16];
#pragma unroll
      for (int q = 0; q < 16; ++q) red[q] = 0.f;
#pragma unroll
      for (int g = 0; g < 3; ++g) {
        const float4* wx = (const float4*)(p.Wih1 + (size_t)(g * H_ + j) * H_);
        float* dx = (g < 2) ? &red[g * 4] : &red[8];
#pragma unroll
        for (int c = 0; c < 4; ++c) {
          float4 w = wx[l + 32 * c];
#pragma unroll
          for (int b2 = 0; b2 < 4; ++b2) {
            const float* a = &sx[b2 * 512 + 4 * l + 128 * c];
            dx[b2] = fmaf(w.x, a[0], dx[b2]); dx[b2] = fmaf(w.y, a[1], dx[b2]);
            dx[b2] = fmaf(w.z, a[2], dx[b2]); dx[b2] = fmaf(w.w, a[3], dx[b2]);
          }
        }
        const float4* wh = (const float4*)(p.Whh1 + (size_t)(g * H_ + j) * H_);
        float* dh = (g < 2) ? &red[g * 4] : &red[12];
#pragma unroll
        for (int c = 0; c < 4; ++c) {
          float4 w = wh[l + 32 * c];
#pragma unroll
          for (int b2 = 0; b2 < 4; ++b2) {
            const float* a = &sh[b2 * 512 + 4 * l + 128 * c];
            dh[b2] = fmaf(w.x, a[0], dh[b2]); dh[b2] = fmaf(w.y, a[1], dh[b2]);
            dh[b2] = fmaf(w.z, a[2], dh[b2]); dh[b2] = fmaf(w.w, a[3], dh[b2]);
          }
        }
      }
#pragma unroll
      for (int d = 1; d < 32; d <<= 1)
#pragma unroll
        for (int q = 0; q < 16; ++q) red[q] += __shfl_xor(red[q], d);
      if (l < 4) {
        const float rr = sigf(red[l] + p.bih1[j] + p.bhh1[j]);
        const float zz = sigf(red[4 + l] + p.bih1[H_ + j] + p.bhh1[H_ + j]);
        const float nn = tanhf(red[8 + l] + p.bih1[2 * H_ + j] +
                               rr * (red[12 + l] + p.bhh1[2 * H_ + j]));
        const float hp = sh[l * 512 + j];
        const float hnew = (1.f - zz) * nn + zz * hp;
        st_cf(wsf + OFF_H1 + (1 - par) * BH + (size_t)(b4 + l) * H_ + j, hnew);
        hout[u * 4 + l] = hnew;
      }
      __syncthreads();
      if (tx < 32) {   // bf16 pack (2 units / dword) -> h1bf[t]
        const int b2 = tx & 3, pp = tx >> 2;
        const float h0v = hout[(pp * 2) * 4 + b2];
        const float h1v = hout[(pp * 2 + 1) * 4 + b2];
        const unsigned pk = (unsigned)f2bf(h0v) | ((unsigned)f2bf(h1v) << 16);
        st_ci((int*)(h1bf + ((size_t)t * B_ + b4 + b2) * H_ + ug * 16 + pp * 2), (int)pk);
      }
    }
    gbar(barp, ++bi);
    // ======= P3: LDS-resident bf16 MFMA vocab scan; then attention(t+1) =======
    if (bk < ND) {
      const int v0 = bk * 128;
      char* stgB = SMEM;                               // [16][1024B] swizzled bf16 h1
      float (*scrF)[16][4] = (float(*)[16][4])(SMEM + 16384);
      int (*scrI2)[16][2] = (int(*)[16][2])(SMEM + 18432);
      const int w = tx >> 6, l = tx & 63, lr = l & 15, lq = l >> 4;
      for (int bt = 0; bt < 2; ++bt) {
        {  // stage h1bf btile (sc0; swizzled LDS write)
          const ull* src = (const ull*)(h1bf + ((size_t)t * B_ + bt * 16) * H_);
          ull vv[4];
#pragma unroll
          for (int e = 0; e < 4; ++e) {
            const ull* ap = src + (size_t)tx * 4 + e;
            asm volatile("global_load_dwordx2 %0, %1, off sc0 sc1" : "=v"(vv[e]) : "v"(ap));
          }
          asm volatile("s_waitcnt vmcnt(0)" ::: "memory");
#pragma unroll
          for (int e = 0; e < 4; ++e) {
            const int uu = tx * 4 + e;                 // ull index 0..2047
            const int row = uu >> 7, wb = (uu & 127) * 8;
            const int base = wb & ~15, half = wb & 8;
            *(ull*)&stgB[row * 1024 + ((base ^ ((row & 7) << 4)) | half)] = vv[e];
          }
        }
        __syncthreads();
        f32x4 acc = {0.f, 0.f, 0.f, 0.f};
        const int vr = w * 16 + lr;
#pragma unroll
        for (int kc = 0; kc < 16; ++kc) {
          const int koff = kc * 64 + lq * 16;
          bf16x8 a = *(const bf16x8*)&stgB[lr * 1024 + (koff ^ ((lr & 7) << 4))];
          bf16x8 bf = *(const bf16x8*)&woL[vr * 1024 + (koff ^ ((lr & 7) << 4))];
          acc = __builtin_amdgcn_mfma_f32_16x16x32_bf16(a, bf, acc, 0, 0, 0);
        }
        const float bov = p.bo[v0 + vr];
#pragma unroll
        for (int r = 0; r < 4; ++r) {
          float v1 = acc[r] + bov, v2 = -3.0e38f;
          int i1 = v0 + vr, i2 = 0x7fffffff;
          float m = v1, s = 1.0f;
#pragma unroll
          for (int d = 1; d < 16; d <<= 1) {
            float w1 = __shfl_xor(v1, d); int j1 = __shfl_xor(i1, d);
            float w2 = __shfl_xor(v2, d); int j2 = __shfl_xor(i2, d);
            float m2 = __shfl_xor(m, d);  float s2 = __shfl_xor(s, d);
            if (w1 > v1 || (w1 == v1 && j1 < i1)) { v2 = v1; i2 = i1; v1 = w1; i1 = j1; }
            else if (w1 > v2 || (w1 == v2 && j1 < i2)) { v2 = w1; i2 = j1; }
            if (w2 > v2 || (w2 == v2 && j2 < i2)) {
              if (w2 > v1 || (w2 == v1 && j2 < i1)) { v2 = v1; i2 = i1; v1 = w2; i1 = j2; }
              else { v2 = w2; i2 = j2; }
            }
            lse_merge(m, s, m2, s2);
          }
          if (lr == 0) {
            const int bb = lq * 4 + r;
            scrF[w][bb][0] = v1; scrF[w][bb][1] = v2;
            scrF[w][bb][2] = m;  scrF[w][bb][3] = s;
            scrI2[w][bb][0] = i1; scrI2[w][bb][1] = i2;
          }
        }
        __syncthreads();
        if (tx < 16) {   // combine 8 waves, publish per-block partials
          float v1 = scrF[0][tx][0], v2 = scrF[0][tx][1];
          float m = scrF[0][tx][2], s = scrF[0][tx][3];
          int i1 = scrI2[0][tx][0], i2 = scrI2[0][tx][1];
#pragma unroll
          for (int ww = 1; ww < 8; ++ww) {
            float w1 = scrF[ww][tx][0]; int j1 = scrI2[ww][tx][0];
            float w2 = scrF[ww][tx][1]; int j2 = scrI2[ww][tx][1];
            if (w1 > v1 || (w1 == v1 && j1 < i1)) { v2 = v1; i2 = i1; v1 = w1; i1 = j1; }
            else if (w1 > v2 || (w1 == v2 && j1 < i2)) { v2 = w1; i2 = j1; }
            if (w2 > v2 || (w2 == v2 && j2 < i2)) {
              if (w2 > v1 || (w2 == v1 && j2 < i1)) { v2 = v1; i2 = i1; v1 = w2; i1 = j2; }
              else { v2 = w2; i2 = j2; }
            }
            lse_merge(m, s, scrF[ww][tx][2], scrF[ww][tx][3]);
          }
          const int b = bt * 16 + tx;
          st_cf(wsf + OFF_A2V + (size_t)b * 512 + bk * 2, v1);
          st_cf(wsf + OFF_A2V + (size_t)b * 512 + bk * 2 + 1, v2);
          st_ci(wsi + OFF_A2I + (size_t)b * 512 + bk * 2, i1);
          st_ci(wsi + OFF_A2I + (size_t)b * 512 + bk * 2 + 1, i2);
          st_cf(wsf + OFF_LSM + (size_t)b * 256 + bk, m);
          st_cf(wsf + OFF_LSS + (size_t)b * 256 + bk, s);
        }
        __syncthreads();
      }
    }
    if (bk < B_ && t < T_ - 1) {      // attention for step t+1 (after scan publish)
      const int b = bk;
      __syncthreads();
      float* rv = (float*)SMEM;                 // [512]
      float* sh1a = (float*)(SMEM + 2048);      // [512]
      sh1a[tx] = ld_cf(wsf + OFF_H1 + (1 - par) * BH + (size_t)b * H_ + tx);
      __syncthreads();
      rv[tx] = sh1a[tx] * p.Wa[tx];
      __syncthreads();
      if (tx < 64) {
        float v = 0.f;
#pragma unroll
        for (int o = 0; o < 8; ++o) v += rv[tx + o * 64];
#pragma unroll
        for (int d = 1; d < 64; d <<= 1) v += __shfl_xor(v, d);
        if (tx == 0) shsS = v;
      }
      __syncthreads();
      if (tx < S_) {
        float sc = tanhf(shsS + wsf[OFF_CS + b * S_ + tx]);
        float e = expf(sc); float sum = e;
#pragma unroll
        for (int d = 1; d < 64; d <<= 1) sum += __shfl_xor(sum, d);
        float w2 = e / sum; wlds[tx] = w2;
        p.out[(size_t)B_ * T_ * V_ + ((size_t)b * T_ + (t + 1)) * S_ + tx] = w2;
      }
      __syncthreads();
      float a0 = 0.f;
      const float* cb = p.ctx + (size_t)b * S_ * C_ + tx;
#pragma unroll 8
      for (int s2 = 0; s2 < S_; ++s2) a0 = fmaf(wlds[s2], cb[(size_t)s2 * C_], a0);
      st_cf(wsf + OFF_INP + (size_t)b * H_ + tx, a0);
    }
    if (t < T_ - 1) gbar(barp, ++bi);
  }
}

// ---------------- epilogue: lse for last step ----------------
__global__ void __launch_bounds__(256) epi_lse(float* __restrict__ wsf) {
  const int b = blockIdx.x, tx = threadIdx.x;
  __shared__ float rm[256], rs[256];
  rm[tx] = (tx < ND) ? wsf[OFF_LSM + b * 256 + tx] : -3.0e38f;
  rs[tx] = (tx < ND) ? wsf[OFF_LSS + b * 256 + tx] : 0.f;
  __syncthreads();
  if (tx < 64) {
    float m = rm[tx], s = rs[tx];
#pragma unroll
    for (int o = 64; o < 256; o += 64) lse_merge(m, s, rm[tx + o], rs[tx + o]);
#pragma unroll
    for (int d = 1; d < 64; d <<= 1) {
      float m2 = __shfl_xor(m, d), s2 = __shfl_xor(s, d);
      lse_merge(m, s, m2, s2);
    }
    if (tx == 0) wsf[OFF_LSEA + 31 * B_ + b] = m + logf(s);
  }
}

// ---------------- final batched logp GEMM (bf16 MFMA) ----------------
__global__ void __launch_bounds__(256) gemm_logp(const unsigned short* __restrict__ h1bf,
                                                 const unsigned short* __restrict__ wobf,
                                                 const float* __restrict__ bo,
                                                 const float* __restrict__ lsea,
                                                 float* __restrict__ out) {
  __shared__ __align__(16) unsigned short As[2][128 * 40];  // rows padded to 80B
  __shared__ __align__(16) unsigned short Bs[2][128 * 40];
  const int tx = threadIdx.x;
  const int v0 = blockIdx.x * 128, m0 = blockIdx.y * 128;
  const int w = tx >> 6, l = tx & 63;
  const int wm = w >> 1, wn = w & 1;
  f32x4 acc[4][4];
#pragma unroll
  for (int i = 0; i < 4; ++i)
#pragma unroll
    for (int j = 0; j < 4; ++j) acc[i][j] = (f32x4){0.f, 0.f, 0.f, 0.f};

#define GSTAGE(ci, kc) {                                                        \
    _Pragma("unroll")                                                           \
    for (int e = 0; e < 2; ++e) {                                               \
      const int seg = tx * 2 + e, row = seg >> 2, s = seg & 3;                  \
      *(uint4*)&As[ci][row * 40 + s * 8] =                                      \
          *(const uint4*)(h1bf + (size_t)(m0 + row) * H_ + (kc) * 32 + s * 8);  \
      *(uint4*)&Bs[ci][row * 40 + s * 8] =                                      \
          *(const uint4*)(wobf + (size_t)(v0 + row) * H_ + (kc) * 32 + s * 8);  \
    } }

  GSTAGE(0, 0);
  __syncthreads();
  for (int kc = 0; kc < 16; ++kc) {
    const int cur = kc & 1;
    if (kc < 15) GSTAGE(cur ^ 1, kc + 1);
    const int lk = (l >> 4) * 8, lr = l & 15;
    bf16x8 af[4], bf[4];
#pragma unroll
    for (int f = 0; f < 4; ++f) {
      af[f] = *(const bf16x8*)&As[cur][(wm * 64 + f * 16 + lr) * 40 + lk];
      bf[f] = *(const bf16x8*)&Bs[cur][(wn * 64 + f * 16 + lr) * 40 + lk];
    }
#pragma unroll
    for (int fm = 0; fm < 4; ++fm)
#pragma unroll
      for (int fn = 0; fn < 4; ++fn)
        acc[fm][fn] = __builtin_amdgcn_mfma_f32_16x16x32_bf16(af[fm], bf[fn], acc[fm][fn], 0, 0, 0);
    __syncthreads();
  }
#undef GSTAGE
  const int lr = l & 15, lq = l >> 4;
#pragma unroll
  for (int fm = 0; fm < 4; ++fm) {
#pragma unroll
    for (int fn = 0; fn < 4; ++fn) {
      const int v = v0 + wn * 64 + fn * 16 + lr;
      const float bov = bo[v];
#pragma unroll
      for (int r = 0; r < 4; ++r) {
        const int M = m0 + wm * 64 + fm * 16 + lq * 4 + r;
        const int tt = M >> 5, b = M & 31;
        out[((size_t)b * T_ + tt) * (size_t)V_ + v] = acc[fm][fn][r] + bov - lsea[tt * B_ + b];
      }
    }
  }
}

// ---------------- host launch ----------------
extern "C" void kernel_launch(void* const* d_in, const int* in_sizes, int n_in,
                              void* d_out, int out_size, void* d_ws, size_t ws_size,
                              hipStream_t stream) {
  (void)in_sizes; (void)n_in; (void)out_size;
  if (ws_size < (size_t)WS_FLOATS * sizeof(float)) return;  // workspace too small

  const float* ctx   = (const float*)d_in[0];
  // d_in[1] = max_len (scalar, == 32, hardcoded)
  const float* embed = (const float*)d_in[2];
  const float* Wa    = (const float*)d_in[3];
  const float* ba    = (const float*)d_in[4];
  const float* Wih0  = (const float*)d_in[5];
  const float* Whh0  = (const float*)d_in[6];
  const float* bih0  = (const float*)d_in[7];
  const float* bhh0  = (const float*)d_in[8];
  const float* Wih1  = (const float*)d_in[9];
  const float* Whh1  = (const float*)d_in[10];
  const float* bih1  = (const float*)d_in[11];
  const float* bhh1  = (const float*)d_in[12];
  const float* Wo    = (const float*)d_in[13];
  const float* bo    = (const float*)d_in[14];
  float* ws  = (float*)d_ws;
  float* out = (float*)d_out;

  zero_k<<<dim3(256), dim3(256), 0, stream>>>(ws);
  cscore_k<<<dim3(32), dim3(256), 0, stream>>>(ctx, Wa, ba, ws);
  cvt_wobf<<<dim3(16000), dim3(256), 0, stream>>>(Wo, (unsigned short*)(ws + OFF_WOBF));

  Params p;
  p.ctx = ctx; p.embed = embed; p.Wa = Wa;
  p.Wih0 = Wih0; p.Whh0 = Whh0; p.bih0 = bih0; p.bhh0 = bhh0;
  p.Wih1 = Wih1; p.Whh1 = Whh1; p.bih1 = bih1; p.bhh1 = bhh1;
  p.Wo = Wo; p.bo = bo; p.ws = ws; p.out = out;
  mtad_main<<<dim3(NBLK), dim3(NTHR), 0, stream>>>(p);

  epi_lse<<<dim3(32), dim3(256), 0, stream>>>(ws);
  gemm_logp<<<dim3(250, 8), dim3(256), 0, stream>>>(
      (const unsigned short*)(ws + OFF_H1BF), (const unsigned short*)(ws + OFF_WOBF),
      bo, ws + OFF_LSEA, out);
}